// Round 1
// baseline (23015.965 us; speedup 1.0000x reference)
//
#include <hip/hip_runtime.h>
#include <cstdint>

#define N_TOT 30000
#define E_TOT 120000
#define G_TOT 1000

typedef unsigned short u16;
typedef __attribute__((ext_vector_type(8))) short short8;
typedef __attribute__((ext_vector_type(4))) float f32x4;

#define AS1 __attribute__((address_space(1)))
#define AS3 __attribute__((address_space(3)))

// async global->LDS, 16B per lane. LDS dest is wave-uniform base + lane*16.
// flat->AS3 via 32-bit truncation (gfx9+ LDS aperture keeps offset in low 32 bits);
// flat->AS1 is identity.
static __device__ __forceinline__ void gload_lds16(const void* g, void* l) {
  __builtin_amdgcn_global_load_lds((AS1 void*)(uintptr_t)g,
                                   (AS3 void*)(uint32_t)(uintptr_t)l, 16, 0, 0);
}

static __device__ __forceinline__ u16 f2bf(float f) {
  uint32_t u = __float_as_uint(f);
  uint32_t r = (u + 0x7fffu + ((u >> 16) & 1u)) >> 16;  // RTNE
  return (u16)r;
}

// ---------------- deg (edges per dst) and graph node counts ----------------
__global__ void prep_kernel(const int* __restrict__ ei, const int* __restrict__ batch,
                            float* __restrict__ deg, float* __restrict__ gcnt) {
  int t = blockIdx.x * 256 + threadIdx.x;
  if (t < E_TOT) atomicAdd(&deg[ei[E_TOT + t]], 1.0f);
  if (t < N_TOT) atomicAdd(&gcnt[batch[t]], 1.0f);
}

// ---------------- fp32 [K][NN] -> bf16 transposed [NN][K] ----------------
__global__ void cvt_transpose(const float* __restrict__ w, u16* __restrict__ wT,
                              int K, int NN) {
  __shared__ u16 lb[64 * 65];
  const int nbk = K >> 6;
  const int bk = blockIdx.x % nbk, bn = blockIdx.x / nbk;
  const int t = threadIdx.x;
#pragma unroll
  for (int it = 0; it < 16; ++it) {
    int lin = it * 256 + t;
    int r = lin >> 6, c = lin & 63;  // r: k-local, c: n-local
    lb[r * 65 + c] = f2bf(w[(size_t)(bk * 64 + r) * NN + bn * 64 + c]);
  }
  __syncthreads();
#pragma unroll
  for (int it = 0; it < 16; ++it) {
    int lin = it * 256 + t;
    int rn = lin >> 6, ck = lin & 63;  // rn: n-local, ck: k-local
    wT[(size_t)(bn * 64 + rn) * K + bk * 64 + ck] = lb[ck * 65 + rn];
  }
}

// ---------------- H = relu(edge_attr @ ew1 + eb1), bf16, chunk-local ----------------
// block = 256 threads, handles 8 edges; each thread owns 4 consecutive k per pass.
__global__ void edge_h(const float* __restrict__ ea, const float* __restrict__ w1,
                       const float* __restrict__ b1, u16* __restrict__ h,
                       int K, int e_start) {
  __shared__ float eas[8][8];
  const int t = threadIdx.x;
  const long ebase = (long)blockIdx.x * 8;
  if (t < 64) {
    long eg = (long)e_start + ebase + (t >> 3);
    eas[t >> 3][t & 7] = (eg < E_TOT) ? ea[eg * 8 + (t & 7)] : 0.f;
  }
  __syncthreads();
  for (int kp = 0; kp < K; kp += 1024) {
    const int k0 = kp + t * 4;
    float w[8][4];
#pragma unroll
    for (int j = 0; j < 8; ++j) {
      f32x4 v = *(const f32x4*)(w1 + (size_t)j * K + k0);
      w[j][0] = v.x; w[j][1] = v.y; w[j][2] = v.z; w[j][3] = v.w;
    }
    f32x4 bb = *(const f32x4*)(b1 + k0);
#pragma unroll
    for (int e = 0; e < 8; ++e) {
      float a0 = bb.x, a1 = bb.y, a2 = bb.z, a3 = bb.w;
#pragma unroll
      for (int j = 0; j < 8; ++j) {
        float aj = eas[e][j];
        a0 += aj * w[j][0]; a1 += aj * w[j][1];
        a2 += aj * w[j][2]; a3 += aj * w[j][3];
      }
      ushort4 ov;
      ov.x = f2bf(fmaxf(a0, 0.f)); ov.y = f2bf(fmaxf(a1, 0.f));
      ov.z = f2bf(fmaxf(a2, 0.f)); ov.w = f2bf(fmaxf(a3, 0.f));
      *(ushort4*)(h + (size_t)(ebase + e) * K + k0) = ov;
    }
  }
}

// ---------------- fused GEMM (H @ ew2) + per-edge matvec fold + scatter ----------------
// 128 edges per block, 4 waves in 2x2; each wave owns a 64x64 C tile (4x4 frags of
// 16x16x32 bf16 MFMA). K processed in 1024-segments (LLC residency of A re-reads);
// after each (seg, n-tile) the partial C is folded into per-wave msg registers:
//   msg[m][o] += x[src_m][i0] * (C[m][o] + eb2)   with i0 = column-block / 64.
// End: combine wave pairs via LDS, atomicAdd into agg[dst].
__global__ __launch_bounds__(256, 2) void gemm_fold(
    const u16* __restrict__ hbuf, const u16* __restrict__ w2T,
    const float* __restrict__ eb2, const float* __restrict__ xin,
    const int* __restrict__ srcA, const int* __restrict__ dstA,
    float* __restrict__ agg, int K, int NN, int din, int e_start, int e_cnt) {
  __shared__ char smem[32768];
  u16* Alds = (u16*)smem;             // [128][64] bf16, XOR-swizzled
  u16* Blds = (u16*)(smem + 16384);   // [128][64] bf16, XOR-swizzled
  float* msgbuf = (float*)smem;       // aliased [128][64] f32 (epilogue only)

  const int t = threadIdx.x;
  const int lane = t & 63;
  const int wid = t >> 6;
  const int mw = wid >> 1, nw = wid & 1;
  const int q = lane >> 4, u = lane & 15;
  const int m0 = blockIdx.x << 7;

  int srcs[16];
#pragma unroll
  for (int fm = 0; fm < 4; ++fm)
#pragma unroll
    for (int r = 0; r < 4; ++r) {
      int m = mw * 64 + fm * 16 + q * 4 + r;
      srcs[fm * 4 + r] = (m0 + m < e_cnt) ? srcA[e_start + m0 + m] : -1;
    }

  f32x4 msg[4][4];
#pragma unroll
  for (int i = 0; i < 4; ++i)
#pragma unroll
    for (int j = 0; j < 4; ++j) msg[i][j] = (f32x4){0.f, 0.f, 0.f, 0.f};

  const int srow = lane >> 3;  // row-in-call 0..7
  const int cb = lane & 7;     // 16B block within 128B row
  const int ntiles = NN >> 7;

  for (int kseg = 0; kseg < K; kseg += 1024) {
    const float bs = (kseg == 0) ? 1.f : 0.f;  // add eb2 only once
    for (int nt = 0; nt < ntiles; ++nt) {
      const int nbase = nt << 7;
      f32x4 acc[4][4];
#pragma unroll
      for (int i = 0; i < 4; ++i)
#pragma unroll
        for (int j = 0; j < 4; ++j) acc[i][j] = (f32x4){0.f, 0.f, 0.f, 0.f};

      for (int k0 = kseg; k0 < kseg + 1024; k0 += 64) {
#pragma unroll
        for (int tt = 0; tt < 4; ++tt) {
          const int call = wid * 4 + tt;
          const int row = call * 8 + srow;
          const int cbg = cb ^ (row & 7);  // XOR swizzle vs row
          gload_lds16(hbuf + (size_t)(m0 + row) * K + k0 + cbg * 8,
                      smem + call * 1024);
          gload_lds16(w2T + (size_t)(nbase + row) * K + k0 + cbg * 8,
                      smem + 16384 + call * 1024);
        }
        __syncthreads();
#pragma unroll
        for (int ks = 0; ks < 2; ++ks) {
          const int kb = ks * 4 + q;
          const int sw = (kb ^ (u & 7)) << 3;
          short8 av[4], bv[4];
#pragma unroll
          for (int fm = 0; fm < 4; ++fm) {
            int m = mw * 64 + fm * 16 + u;
            av[fm] = *(const short8*)(Alds + m * 64 + sw);
          }
#pragma unroll
          for (int fn = 0; fn < 4; ++fn) {
            int n = nw * 64 + fn * 16 + u;
            bv[fn] = *(const short8*)(Blds + n * 64 + sw);
          }
#pragma unroll
          for (int fm = 0; fm < 4; ++fm)
#pragma unroll
            for (int fn = 0; fn < 4; ++fn)
              acc[fm][fn] = __builtin_amdgcn_mfma_f32_16x16x32_bf16(
                  av[fm], bv[fn], acc[fm][fn], 0, 0, 0);
        }
        __syncthreads();
      }

      // fold partial C into msg registers
      const int i0 = nt * 2 + nw;  // which x-input dim this 64-col block multiplies
      float ebv[4];
#pragma unroll
      for (int fn = 0; fn < 4; ++fn)
        ebv[fn] = eb2[nbase + nw * 64 + fn * 16 + u] * bs;
      f32x4 xv[4];
#pragma unroll
      for (int fm = 0; fm < 4; ++fm)
#pragma unroll
        for (int r = 0; r < 4; ++r) {
          int s = srcs[fm * 4 + r];
          xv[fm][r] = (s >= 0) ? xin[(size_t)s * din + i0] : 0.f;
        }
#pragma unroll
      for (int fm = 0; fm < 4; ++fm)
#pragma unroll
        for (int fn = 0; fn < 4; ++fn) {
          f32x4 w4 = acc[fm][fn];
          float e4 = ebv[fn];
          w4.x += e4; w4.y += e4; w4.z += e4; w4.w += e4;
          msg[fm][fn] += xv[fm] * w4;
        }
    }
  }

  // combine the two waves sharing each m-half, then scatter to agg[dst]
  __syncthreads();
  if (nw == 0) {
#pragma unroll
    for (int fm = 0; fm < 4; ++fm)
#pragma unroll
      for (int fn = 0; fn < 4; ++fn)
#pragma unroll
        for (int r = 0; r < 4; ++r) {
          int m = mw * 64 + fm * 16 + q * 4 + r;
          msgbuf[m * 64 + fn * 16 + u] = msg[fm][fn][r];
        }
  }
  __syncthreads();
  if (nw == 1) {
#pragma unroll
    for (int fm = 0; fm < 4; ++fm)
#pragma unroll
      for (int fn = 0; fn < 4; ++fn)
#pragma unroll
        for (int r = 0; r < 4; ++r) {
          int m = mw * 64 + fm * 16 + q * 4 + r;
          msgbuf[m * 64 + fn * 16 + u] += msg[fm][fn][r];
        }
  }
  __syncthreads();
  const int oo = t & 63;
  for (int ml = t >> 6; ml < 128; ml += 4) {
    if (m0 + ml < e_cnt) {
      int d = dstA[e_start + m0 + ml];
      atomicAdd(&agg[(size_t)d * 64 + oo], msgbuf[ml * 64 + oo]);
    }
  }
}

// ---------------- out = relu(agg/deg + x@root + cb) ----------------
__global__ void node_update(const float* __restrict__ agg, const float* __restrict__ deg,
                            const float* __restrict__ xin, const float* __restrict__ root,
                            const float* __restrict__ cbv, float* __restrict__ xout,
                            int din) {
  __shared__ float rl[4096];
  const int t = threadIdx.x;
  for (int i = t; i < din * 64; i += 256) rl[i] = root[i];
  __syncthreads();
  const int o = t & 63;
  const int n = blockIdx.x * 4 + (t >> 6);
  if (n >= N_TOT) return;
  float acc = cbv[o];
  for (int i = 0; i < din; ++i) acc += xin[(size_t)n * din + i] * rl[i * 64 + o];
  float d = deg[n];
  d = d > 1.f ? d : 1.f;
  acc += agg[(size_t)n * 64 + o] / d;
  xout[(size_t)n * 64 + o] = acc > 0.f ? acc : 0.f;
}

// ---------------- graph sum pool ----------------
__global__ void pool_kernel(const float* __restrict__ x3, const int* __restrict__ batch,
                            float* __restrict__ gsum) {
  int t = blockIdx.x * 256 + threadIdx.x;
  if (t >= N_TOT * 64) return;
  int n = t >> 6, o = t & 63;
  atomicAdd(&gsum[(size_t)batch[n] * 64 + o], x3[t]);
}

// ---------------- readout MLP: relu(g@mw1+mb1)@mw2+mb2 ----------------
__global__ void readout_kernel(const float* __restrict__ gsum, const float* __restrict__ gcnt,
                               const float* __restrict__ mw1, const float* __restrict__ mb1,
                               const float* __restrict__ mw2, const float* __restrict__ mb2,
                               float* __restrict__ out) {
  __shared__ float gv[4][64];
  const int t = threadIdx.x;
  const int o = t & 63, loc = t >> 6;
  const int g = blockIdx.x * 4 + loc;
  float v = 0.f;
  if (g < G_TOT) {
    float c = gcnt[g];
    c = c > 1.f ? c : 1.f;
    v = gsum[(size_t)g * 64 + o] / c;
  }
  gv[loc][o] = v;
  __syncthreads();
  float acc = mb1[o];
  for (int i = 0; i < 64; ++i) acc += gv[loc][i] * mw1[i * 64 + o];
  acc = acc > 0.f ? acc : 0.f;
  float p = acc * mw2[o];
#pragma unroll
  for (int off = 32; off > 0; off >>= 1) p += __shfl_down(p, off, 64);
  if (o == 0 && g < G_TOT) out[g] = p + mb2[0];
}

extern "C" void kernel_launch(void* const* d_in, const int* in_sizes, int n_in,
                              void* d_out, int out_size, void* d_ws, size_t ws_size,
                              hipStream_t stream) {
  const float* x     = (const float*)d_in[0];
  const int*   ei    = (const int*)d_in[1];
  const float* ea    = (const float*)d_in[2];
  const int*   batch = (const int*)d_in[3];
  const float* ew1[3] = {(const float*)d_in[4],  (const float*)d_in[10], (const float*)d_in[16]};
  const float* eb1[3] = {(const float*)d_in[5],  (const float*)d_in[11], (const float*)d_in[17]};
  const float* ew2[3] = {(const float*)d_in[6],  (const float*)d_in[12], (const float*)d_in[18]};
  const float* eb2[3] = {(const float*)d_in[7],  (const float*)d_in[13], (const float*)d_in[19]};
  const float* root[3] = {(const float*)d_in[8],  (const float*)d_in[14], (const float*)d_in[20]};
  const float* cbv[3]  = {(const float*)d_in[9],  (const float*)d_in[15], (const float*)d_in[21]};
  const float* mw1 = (const float*)d_in[22];
  const float* mb1 = (const float*)d_in[23];
  const float* mw2 = (const float*)d_in[24];
  const float* mb2 = (const float*)d_in[25];
  float* out = (float*)d_out;

  char* p = (char*)d_ws;
  auto carve = [&p](size_t bytes) {
    char* r = p;
    p += (bytes + 255) & ~(size_t)255;
    return r;
  };
  u16*   w2T  = (u16*)carve((size_t)4096 * 4096 * 2);  // shared per-layer B^T (bf16)
  float* x1   = (float*)carve((size_t)N_TOT * 64 * 4);
  float* x2   = (float*)carve((size_t)N_TOT * 64 * 4);
  float* x3   = (float*)carve((size_t)N_TOT * 64 * 4);
  float* agg  = (float*)carve((size_t)N_TOT * 64 * 4);
  float* deg  = (float*)carve((size_t)N_TOT * 4);
  float* gsum = (float*)carve((size_t)G_TOT * 64 * 4);
  float* gcnt = (float*)carve((size_t)G_TOT * 4);
  size_t used = (size_t)(p - (char*)d_ws);
  size_t avail = ws_size > used ? ws_size - used : 0;
  u16* hbuf = (u16*)p;  // H chunk, sized to remaining workspace

  hipMemsetAsync(deg, 0, (size_t)N_TOT * 4, stream);
  hipMemsetAsync(gsum, 0, (size_t)G_TOT * 64 * 4, stream);
  hipMemsetAsync(gcnt, 0, (size_t)G_TOT * 4, stream);
  prep_kernel<<<(E_TOT + 255) / 256, 256, 0, stream>>>(ei, batch, deg, gcnt);

  const float* xin_l[3]  = {x, x1, x2};
  float*       xout_l[3] = {x1, x2, x3};
  const int Ks[3]   = {2048, 4096, 4096};  // NN == K for every layer here
  const int dins[3] = {32, 64, 64};

  for (int L = 0; L < 3; ++L) {
    const int K = Ks[L], NN = Ks[L], din = dins[L];
    cvt_transpose<<<(K / 64) * (NN / 64), 256, 0, stream>>>(ew2[L], w2T, K, NN);
    hipMemsetAsync(agg, 0, (size_t)N_TOT * 64 * 4, stream);
    size_t rows_fit = avail / ((size_t)K * 2);
    long chunk = rows_fit > 120064 ? 120064 : (long)rows_fit;
    chunk &= ~127L;
    if (chunk < 128) chunk = 128;  // requires ws >= ~65 MB
    for (long e0 = 0; e0 < E_TOT; e0 += chunk) {
      long cnt = (E_TOT - e0 < chunk) ? (E_TOT - e0) : chunk;
      long cntPad = (cnt + 127) & ~127L;
      edge_h<<<(int)(cntPad / 8), 256, 0, stream>>>(ea, ew1[L], eb1[L], hbuf, K, (int)e0);
      gemm_fold<<<(int)(cntPad / 128), 256, 0, stream>>>(
          hbuf, w2T, eb2[L], xin_l[L], ei, ei + E_TOT, agg, K, NN, din, (int)e0, (int)cnt);
    }
    node_update<<<(N_TOT + 3) / 4, 256, 0, stream>>>(agg, deg, xin_l[L], root[L], cbv[L],
                                                     xout_l[L], din);
  }
  pool_kernel<<<(N_TOT * 64 + 255) / 256, 256, 0, stream>>>(x3, batch, gsum);
  readout_kernel<<<(G_TOT + 3) / 4, 256, 0, stream>>>(gsum, gcnt, mw1, mb1, mw2, mb2, out);
}

// Round 2
// 11944.636 us; speedup vs baseline: 1.9269x; 1.9269x over previous
//
#include <hip/hip_runtime.h>
#include <cstdint>

#define N_TOT 30000
#define E_TOT 120000
#define G_TOT 1000

typedef unsigned short u16;
typedef unsigned int u32;
typedef __attribute__((ext_vector_type(8))) short short8;
typedef __attribute__((ext_vector_type(4))) float f32x4;

#define AS1 __attribute__((address_space(1)))
#define AS3 __attribute__((address_space(3)))

// async global->LDS, 16B per lane. LDS dest must be wave-uniform base + lane*16.
static __device__ __forceinline__ void gload_lds16(const void* g, void* l) {
  __builtin_amdgcn_global_load_lds((AS1 void*)(uintptr_t)g,
                                   (AS3 void*)(uint32_t)(uintptr_t)l, 16, 0, 0);
}

static __device__ __forceinline__ u16 f2bf(float f) {
  uint32_t u = __float_as_uint(f);
  uint32_t r = (u + 0x7fffu + ((u >> 16) & 1u)) >> 16;  // RTNE
  return (u16)r;
}
static __device__ __forceinline__ float bf2f(u16 v) {
  return __uint_as_float((uint32_t)v << 16);
}

// ---------------- deg (in-edges per dst), graph counts, src out-degree ------
__global__ void prep_kernel(const int* __restrict__ ei, const int* __restrict__ batch,
                            float* __restrict__ deg, float* __restrict__ gcnt,
                            int* __restrict__ sd) {
  int t = blockIdx.x * 256 + threadIdx.x;
  if (t < E_TOT) {
    atomicAdd(&deg[ei[E_TOT + t]], 1.0f);
    atomicAdd(&sd[ei[t]], 1);
  }
  if (t < N_TOT) atomicAdd(&gcnt[batch[t]], 1.0f);
}

// ---------------- exclusive scan of src out-degree (single block) ----------
__global__ void scan_kernel(const int* __restrict__ sd, int* __restrict__ off) {
  __shared__ int buf[1024];
  __shared__ int carry;
  const int t = threadIdx.x;
  if (t == 0) carry = 0;
  __syncthreads();
  for (int base = 0; base < N_TOT; base += 1024) {
    int v = base + t;
    int x = (v < N_TOT) ? sd[v] : 0;
    buf[t] = x;
    __syncthreads();
    for (int o = 1; o < 1024; o <<= 1) {
      int y = (t >= o) ? buf[t - o] : 0;
      __syncthreads();
      buf[t] += y;
      __syncthreads();
    }
    if (v < N_TOT) off[v] = carry + buf[t] - x;
    __syncthreads();
    if (t == 0) carry += buf[1023];
    __syncthreads();
  }
  if (t == 0) off[N_TOT] = carry;
}

// ---------------- counting-sort edges by src -------------------------------
__global__ void scatter_kernel(const int* __restrict__ ei, const float* __restrict__ ea,
                               const int* __restrict__ off, int* __restrict__ cur,
                               int* __restrict__ src_s, int* __restrict__ dst_s,
                               float* __restrict__ ea_s) {
  int e = blockIdx.x * 256 + threadIdx.x;
  if (e >= E_TOT) return;
  int s = ei[e];
  int pos = off[s] + atomicAdd(&cur[s], 1);
  src_s[pos] = s;
  dst_s[pos] = ei[E_TOT + e];
#pragma unroll
  for (int j = 0; j < 8; ++j) ea_s[(size_t)pos * 8 + j] = ea[(size_t)e * 8 + j];
}

// ---------------- permute ew2 -> Wp[(kb*2+oh)*128 + c][i] bf16 -------------
// c = kc*32 + o' with k = kb*4+kc, o = oh*32+o'
__global__ void cvt_wp(const float* __restrict__ ew2, u16* __restrict__ wp,
                       int K, int DINp) {
  int idx = blockIdx.x * 256 + threadIdx.x;  // (kbh, c)
  int c = idx & 127, kbh = idx >> 7;
  int kb = kbh >> 1, oh = kbh & 1;
  int k = kb * 4 + (c >> 5), o = oh * 32 + (c & 31);
  const float* src = ew2 + (size_t)k * (DINp * 64) + o;
  u16* dst = wp + (size_t)idx * DINp;
  for (int i = 0; i < DINp; ++i) dst[i] = f2bf(src[(size_t)i * 64]);
}

// ---------------- fused: M-build (MFMA) + per-edge fold + scatter ----------
// grid = 469 node-groups x 2 o-halves; block = 512 threads (8 waves).
// Per step (4 k's): stage Wp slab [128 c][DIN] bf16 -> MFMA M[64v x 128c] ->
// LDS bf16 (16B-granule v-swizzle) -> fold into per-edge msg regs with H
// recomputed on the fly from ea (8-dim). End: + bias-term, atomic scatter.
template <int DIN>
__global__ __launch_bounds__(512, 4) void fused_conv(
    const u16* __restrict__ Wp, const float* __restrict__ ew1,
    const float* __restrict__ eb1, const float* __restrict__ eb2,
    const float* __restrict__ xin, const float* __restrict__ eas,
    const int* __restrict__ src_s, const int* __restrict__ dst_s,
    const int* __restrict__ node_off, float* __restrict__ agg, int K) {
  constexpr int KF = DIN / 32;  // mfma k-fragments (i-dim)
  constexpr int NB = DIN / 8;   // 16B granules per Wp row
  constexpr int L_XB = 0;                     // [64][DIN] u16
  constexpr int L_WP = 64 * DIN * 2;          // [128][DIN] u16 (swizzled)
  constexpr int L_MS = L_WP + 128 * DIN * 2;  // [64][128] bf16 (swizzled)
  constexpr int L_HS = L_MS + 16384;          // [512][4] u16
  constexpr int L_EA = L_HS + 4096;           // [512][8] f32
  constexpr int L_VL = L_EA + 16384;          // [512] int
  __shared__ char smem[L_VL + 2048];

  const int t = threadIdx.x;
  const int lane = t & 63, wave = t >> 6;
  const int u = lane & 15, q = lane >> 4;
  const int grp = blockIdx.x >> 1, oh = blockIdx.x & 1;
  const int v0 = grp * 64;
  const int e0 = node_off[v0];
  const int v1 = (v0 + 64 < N_TOT) ? v0 + 64 : N_TOT;
  int Eblk = node_off[v1] - e0;
  if (Eblk > 512) Eblk = 512;

  // stage x group (bf16)
  {
    int row = t >> 3, i0 = (t & 7) * (DIN / 8);
    u16* xb = (u16*)(smem + L_XB) + row * DIN + i0;
    int vg = v0 + row;
#pragma unroll
    for (int j = 0; j < DIN / 8; ++j)
      xb[j] = (vg < N_TOT) ? f2bf(xin[(size_t)vg * DIN + i0 + j]) : (u16)0;
  }
  // stage edge attrs + local src ids
  {
    float* ev = (float*)(smem + L_EA) + t * 8;
    int vl = 0;
    if (t < Eblk) {
      const float* s = eas + (size_t)(e0 + t) * 8;
#pragma unroll
      for (int j = 0; j < 8; ++j) ev[j] = s[j];
      vl = src_s[e0 + t] - v0;
    } else {
#pragma unroll
      for (int j = 0; j < 8; ++j) ev[j] = 0.f;
    }
    ((int*)(smem + L_VL))[t] = vl;
  }
  __syncthreads();

  // cache x fragments (B-operand: B[k=i][n=v])
  short8 bfr[4][KF];
#pragma unroll
  for (int vt = 0; vt < 4; ++vt)
#pragma unroll
    for (int kf = 0; kf < KF; ++kf)
      bfr[vt][kf] =
          *(const short8*)(smem + L_XB + ((vt * 16 + u) * DIN + (kf * 4 + q) * 8) * 2);

  // fold task registers: task (slot = t>>1 + p*256, oq = t&1)
  const int oq = t & 1;
  int vofs[2], vswz[2], slotp[2];
#pragma unroll
  for (int p = 0; p < 2; ++p) {
    int s = (t >> 1) + p * 256;
    slotp[p] = s;
    int vl = ((int*)(smem + L_VL))[s];
    vofs[p] = L_MS + vl * 256;
    vswz[p] = vl & 7;
  }
  f32x4 msg[2][4];
#pragma unroll
  for (int p = 0; p < 2; ++p)
#pragma unroll
    for (int j = 0; j < 4; ++j) msg[p][j] = (f32x4){0.f, 0.f, 0.f, 0.f};

  const size_t slab = (size_t)128 * DIN;
  const int nsteps = K >> 2;
  for (int kb = 0; kb < nsteps; ++kb) {
    // s1: async stage Wp slab (swizzled granules)
    const u16* gsl = Wp + (size_t)(kb * 2 + oh) * slab;
#pragma unroll
    for (int j = 0; j < NB / 4; ++j) {
      int s = j * 512 + t;
      int c = s / NB, ib = s % NB;
      gload_lds16(gsl + (c * NB + (ib ^ (c & (NB - 1)))) * 8, smem + L_WP + s * 16);
    }
    // s2: H chunk for own slot (recompute from ea)
    {
      const float* ev = (const float*)(smem + L_EA) + t * 8;
      f32x4 ea0 = *(const f32x4*)ev, ea1 = *(const f32x4*)(ev + 4);
      ushort4 hv;
      u16* hp = (u16*)&hv;
      const int kk = kb * 4;
#pragma unroll
      for (int kc = 0; kc < 4; ++kc) {
        int k = kk + kc;
        float a = eb1[k];
        a += ea0.x * ew1[0 * K + k] + ea0.y * ew1[1 * K + k] +
             ea0.z * ew1[2 * K + k] + ea0.w * ew1[3 * K + k];
        a += ea1.x * ew1[4 * K + k] + ea1.y * ew1[5 * K + k] +
             ea1.z * ew1[6 * K + k] + ea1.w * ew1[7 * K + k];
        hp[kc] = f2bf(a > 0.f ? a : 0.f);
      }
      *(ushort4*)(smem + L_HS + t * 8) = hv;
    }
    __syncthreads();  // drains gload + Hs writes

    // s4: MFMA  M[c=16 rows of this wave][64 v]
    {
      f32x4 acc[4];
#pragma unroll
      for (int vt = 0; vt < 4; ++vt) acc[vt] = (f32x4){0.f, 0.f, 0.f, 0.f};
      const int crow = wave * 16 + u;
#pragma unroll
      for (int kf = 0; kf < KF; ++kf) {
        short8 afr = *(const short8*)(
            smem + L_WP + (crow * DIN + (((kf * 4 + q) ^ (crow & (NB - 1))) * 8)) * 2);
#pragma unroll
        for (int vt = 0; vt < 4; ++vt)
          acc[vt] = __builtin_amdgcn_mfma_f32_16x16x32_bf16(afr, bfr[vt][kf], acc[vt], 0, 0, 0);
      }
      // s5: write M chunk as bf16, 16B-granule swizzle by v
#pragma unroll
      for (int vt = 0; vt < 4; ++vt) {
        int v = vt * 16 + u;
        uint2 pk;
        pk.x = ((u32)f2bf(acc[vt].y) << 16) | f2bf(acc[vt].x);
        pk.y = ((u32)f2bf(acc[vt].w) << 16) | f2bf(acc[vt].z);
        int bbG = ((wave << 1) | (q >> 1)) ^ (v & 7);
        *(uint2*)(smem + L_MS + v * 256 + bbG * 16 + (q & 1) * 8) = pk;
      }
    }
    __syncthreads();

    // s7: fold M-chunk into msg regs
#pragma unroll
    for (int p = 0; p < 2; ++p) {
      if (wave * 32 + p * 256 < Eblk) {
        ushort4 h4 = *(const ushort4*)(smem + L_HS + slotp[p] * 8);
        const u16* hp = (const u16*)&h4;
#pragma unroll
        for (int kc = 0; kc < 4; ++kc) {
          float h = bf2f(hp[kc]);
#pragma unroll
          for (int s = 0; s < 2; ++s) {
            int bb = (kc * 4 + oq * 2 + s) ^ vswz[p];
            uint4 m8 = *(const uint4*)(smem + vofs[p] + bb * 16);
            f32x4 lo, hi;
            lo.x = __uint_as_float(m8.x << 16);
            lo.y = __uint_as_float(m8.x & 0xffff0000u);
            lo.z = __uint_as_float(m8.y << 16);
            lo.w = __uint_as_float(m8.y & 0xffff0000u);
            hi.x = __uint_as_float(m8.z << 16);
            hi.y = __uint_as_float(m8.z & 0xffff0000u);
            hi.z = __uint_as_float(m8.w << 16);
            hi.w = __uint_as_float(m8.w & 0xffff0000u);
            msg[p][s * 2 + 0] += h * lo;
            msg[p][s * 2 + 1] += h * hi;
          }
        }
      }
    }
    __syncthreads();
  }

  // bias term bt[v][o'] = sum_i x[v,i]*eb2[i*64 + oh*32 + o']  (into Ms area)
  {
    int v = t >> 3, o4 = (t & 7) * 4;
    f32x4 acc = (f32x4){0.f, 0.f, 0.f, 0.f};
    const u16* xb = (const u16*)(smem + L_XB) + v * DIN;
    const float* ep = eb2 + oh * 32 + o4;
    for (int i = 0; i < DIN; ++i) {
      float xv = bf2f(xb[i]);
      f32x4 w4 = *(const f32x4*)(ep + (size_t)i * 64);
      acc += xv * w4;
    }
    *(f32x4*)(smem + L_MS + (v * 32 + o4) * 4) = acc;
  }
  __syncthreads();

  // scatter: agg[dst, oh*32 + oq*16 + 0..15] += msg + bt
#pragma unroll
  for (int p = 0; p < 2; ++p) {
    int slot = slotp[p];
    if (slot < Eblk) {
      int d = dst_s[e0 + slot];
      int vl = (vofs[p] - L_MS) >> 8;
      float* ap = agg + (size_t)d * 64 + oh * 32 + oq * 16;
      const float* bt = (const float*)(smem + L_MS) + vl * 32 + oq * 16;
#pragma unroll
      for (int j = 0; j < 4; ++j) {
        f32x4 m = msg[p][j];
        atomicAdd(ap + j * 4 + 0, m.x + bt[j * 4 + 0]);
        atomicAdd(ap + j * 4 + 1, m.y + bt[j * 4 + 1]);
        atomicAdd(ap + j * 4 + 2, m.z + bt[j * 4 + 2]);
        atomicAdd(ap + j * 4 + 3, m.w + bt[j * 4 + 3]);
      }
    }
  }
}

// ---------------- out = relu(agg/deg + x@root + cb) ----------------
__global__ void node_update(const float* __restrict__ agg, const float* __restrict__ deg,
                            const float* __restrict__ xin, const float* __restrict__ root,
                            const float* __restrict__ cbv, float* __restrict__ xout,
                            int din) {
  __shared__ float rl[4096];
  const int t = threadIdx.x;
  for (int i = t; i < din * 64; i += 256) rl[i] = root[i];
  __syncthreads();
  const int o = t & 63;
  const int n = blockIdx.x * 4 + (t >> 6);
  if (n >= N_TOT) return;
  float acc = cbv[o];
  for (int i = 0; i < din; ++i) acc += xin[(size_t)n * din + i] * rl[i * 64 + o];
  float d = deg[n];
  d = d > 1.f ? d : 1.f;
  acc += agg[(size_t)n * 64 + o] / d;
  xout[(size_t)n * 64 + o] = acc > 0.f ? acc : 0.f;
}

// ---------------- graph sum pool ----------------
__global__ void pool_kernel(const float* __restrict__ x3, const int* __restrict__ batch,
                            float* __restrict__ gsum) {
  int t = blockIdx.x * 256 + threadIdx.x;
  if (t >= N_TOT * 64) return;
  int n = t >> 6, o = t & 63;
  atomicAdd(&gsum[(size_t)batch[n] * 64 + o], x3[t]);
}

// ---------------- readout MLP ----------------
__global__ void readout_kernel(const float* __restrict__ gsum, const float* __restrict__ gcnt,
                               const float* __restrict__ mw1, const float* __restrict__ mb1,
                               const float* __restrict__ mw2, const float* __restrict__ mb2,
                               float* __restrict__ out) {
  __shared__ float gv[4][64];
  const int t = threadIdx.x;
  const int o = t & 63, loc = t >> 6;
  const int g = blockIdx.x * 4 + loc;
  float v = 0.f;
  if (g < G_TOT) {
    float c = gcnt[g];
    c = c > 1.f ? c : 1.f;
    v = gsum[(size_t)g * 64 + o] / c;
  }
  gv[loc][o] = v;
  __syncthreads();
  float acc = mb1[o];
  for (int i = 0; i < 64; ++i) acc += gv[loc][i] * mw1[i * 64 + o];
  acc = acc > 0.f ? acc : 0.f;
  float p = acc * mw2[o];
#pragma unroll
  for (int off = 32; off > 0; off >>= 1) p += __shfl_down(p, off, 64);
  if (o == 0 && g < G_TOT) out[g] = p + mb2[0];
}

extern "C" void kernel_launch(void* const* d_in, const int* in_sizes, int n_in,
                              void* d_out, int out_size, void* d_ws, size_t ws_size,
                              hipStream_t stream) {
  const float* x     = (const float*)d_in[0];
  const int*   ei    = (const int*)d_in[1];
  const float* ea    = (const float*)d_in[2];
  const int*   batch = (const int*)d_in[3];
  const float* ew1[3] = {(const float*)d_in[4],  (const float*)d_in[10], (const float*)d_in[16]};
  const float* eb1[3] = {(const float*)d_in[5],  (const float*)d_in[11], (const float*)d_in[17]};
  const float* ew2[3] = {(const float*)d_in[6],  (const float*)d_in[12], (const float*)d_in[18]};
  const float* eb2[3] = {(const float*)d_in[7],  (const float*)d_in[13], (const float*)d_in[19]};
  const float* root[3] = {(const float*)d_in[8],  (const float*)d_in[14], (const float*)d_in[20]};
  const float* cbv[3]  = {(const float*)d_in[9],  (const float*)d_in[15], (const float*)d_in[21]};
  const float* mw1 = (const float*)d_in[22];
  const float* mb1 = (const float*)d_in[23];
  const float* mw2 = (const float*)d_in[24];
  const float* mb2 = (const float*)d_in[25];
  float* out = (float*)d_out;

  char* p = (char*)d_ws;
  auto carve = [&p](size_t bytes) {
    char* r = p;
    p += (bytes + 255) & ~(size_t)255;
    return r;
  };
  u16*   wp   = (u16*)carve((size_t)4096 * 64 * 64 * 2);  // permuted ew2, per-layer
  float* x1   = (float*)carve((size_t)N_TOT * 64 * 4);
  float* x2   = (float*)carve((size_t)N_TOT * 64 * 4);
  float* x3   = (float*)carve((size_t)N_TOT * 64 * 4);
  float* agg  = (float*)carve((size_t)N_TOT * 64 * 4);
  float* deg  = (float*)carve((size_t)N_TOT * 4);
  float* gsum = (float*)carve((size_t)G_TOT * 64 * 4);
  float* gcnt = (float*)carve((size_t)G_TOT * 4);
  int*   sd   = (int*)carve((size_t)N_TOT * 4);
  int*   noff = (int*)carve((size_t)(N_TOT + 1) * 4);
  int*   cur  = (int*)carve((size_t)N_TOT * 4);
  int*   srcs = (int*)carve((size_t)E_TOT * 4);
  int*   dsts = (int*)carve((size_t)E_TOT * 4);
  float* eass = (float*)carve((size_t)E_TOT * 8 * 4);

  hipMemsetAsync(deg, 0, (size_t)N_TOT * 4, stream);
  hipMemsetAsync(gsum, 0, (size_t)G_TOT * 64 * 4, stream);
  hipMemsetAsync(gcnt, 0, (size_t)G_TOT * 4, stream);
  hipMemsetAsync(sd, 0, (size_t)N_TOT * 4, stream);
  hipMemsetAsync(cur, 0, (size_t)N_TOT * 4, stream);

  prep_kernel<<<(E_TOT + 255) / 256, 256, 0, stream>>>(ei, batch, deg, gcnt, sd);
  scan_kernel<<<1, 1024, 0, stream>>>(sd, noff);
  scatter_kernel<<<(E_TOT + 255) / 256, 256, 0, stream>>>(ei, ea, noff, cur, srcs, dsts, eass);

  const float* xin_l[3]  = {x, x1, x2};
  float*       xout_l[3] = {x1, x2, x3};
  const int Ks[3]   = {2048, 4096, 4096};
  const int dins[3] = {32, 64, 64};
  const int grid_fused = ((N_TOT + 63) / 64) * 2;  // 938

  for (int L = 0; L < 3; ++L) {
    const int K = Ks[L], din = dins[L];
    cvt_wp<<<(K * 64) / 256, 256, 0, stream>>>(ew2[L], wp, K, din);
    hipMemsetAsync(agg, 0, (size_t)N_TOT * 64 * 4, stream);
    if (din == 32)
      fused_conv<32><<<grid_fused, 512, 0, stream>>>(wp, ew1[L], eb1[L], eb2[L], xin_l[L],
                                                     eass, srcs, dsts, noff, agg, K);
    else
      fused_conv<64><<<grid_fused, 512, 0, stream>>>(wp, ew1[L], eb1[L], eb2[L], xin_l[L],
                                                     eass, srcs, dsts, noff, agg, K);
    node_update<<<(N_TOT + 3) / 4, 256, 0, stream>>>(agg, deg, xin_l[L], root[L], cbv[L],
                                                     xout_l[L], din);
  }
  pool_kernel<<<(N_TOT * 64 + 255) / 256, 256, 0, stream>>>(x3, batch, gsum);
  readout_kernel<<<(G_TOT + 3) / 4, 256, 0, stream>>>(gsum, gcnt, mw1, mb1, mw2, mb2, out);
}